// Round 1
// baseline (193.360 us; speedup 1.0000x reference)
//
#include <hip/hip_runtime.h>
#include <math.h>

// CapsuleLayer dynamic routing, fully fused, zero-workspace.
// B=256, IN_CAPS=1152, IN_DIM=8, OUT_CAPS=10, OUT_DIM=16, ROUTINGS=3.
//
// Algebra: b_t[i,j] = (sum_{t'<t} v_t')[j,:] . u_hat[i,j,:]  (b starts at 0),
// so we only keep vdot = running sum of outputs; pass 0 has c = 0.1 exactly.
//
// Mapping: grid = 256 blocks (one per batch b). Block = 512 threads =
// 32 groups x 16 lanes; lane = d (output dim), group walks i (36 iters/pass).
// x[b] staged in LDS once; W streamed from global (L2/L3 resident,
// identical traversal order across blocks for temporal locality).

#define B_SZ 256
#define IN_CAPS 1152
#define IN_DIM 8
#define OUT_CAPS 10
#define OUT_DIM 16
#define NGROUPS 32
#define BLOCK_THREADS (NGROUPS * OUT_DIM)   // 512
#define ITERS (IN_CAPS / NGROUPS)           // 36

__global__ __launch_bounds__(BLOCK_THREADS)
void caps_routing_kernel(const float* __restrict__ x,
                         const float* __restrict__ W,
                         float* __restrict__ out) {
    __shared__ __align__(16) float xs[IN_CAPS * IN_DIM];          // 36864 B
    __shared__ float sred[NGROUPS * OUT_CAPS * OUT_DIM];          // 20480 B
    __shared__ float vdot_lds[OUT_CAPS * OUT_DIM];                // 640 B

    const int b   = blockIdx.x;
    const int tid = threadIdx.x;
    const int g   = tid >> 4;      // group 0..31
    const int d   = tid & 15;      // lane within group = output dim

    // ---- stage x[b] into LDS (coalesced float4) ----
    {
        const float4* xg = reinterpret_cast<const float4*>(x + (size_t)b * IN_CAPS * IN_DIM);
        float4* xl = reinterpret_cast<float4*>(xs);
        for (int t = tid; t < IN_CAPS * IN_DIM / 4; t += BLOCK_THREADS)
            xl[t] = xg[t];
    }
    __syncthreads();

    for (int pass = 0; pass < 3; ++pass) {
        // preload vdot for this lane's d (per j) -- valid for pass >= 1
        float vdot_reg[OUT_CAPS];
        if (pass > 0) {
            #pragma unroll
            for (int j = 0; j < OUT_CAPS; ++j)
                vdot_reg[j] = vdot_lds[j * OUT_DIM + d];
        }

        float s_loc[OUT_CAPS];
        #pragma unroll
        for (int j = 0; j < OUT_CAPS; ++j) s_loc[j] = 0.f;

        for (int it = 0; it < ITERS; ++it) {
            const int i = it * NGROUPS + g;

            // broadcast-read x[b,i,0..7] from LDS
            float xk[IN_DIM];
            {
                const float4* xr = reinterpret_cast<const float4*>(xs + i * IN_DIM);
                float4 a0 = xr[0], a1 = xr[1];
                xk[0] = a0.x; xk[1] = a0.y; xk[2] = a0.z; xk[3] = a0.w;
                xk[4] = a1.x; xk[5] = a1.y; xk[6] = a1.z; xk[7] = a1.w;
            }

            // u_hat[i, j, d] = sum_k x[k] * W[i,j,k,d]
            const float* wp = W + (size_t)i * (OUT_CAPS * IN_DIM * OUT_DIM) + d;
            float u[OUT_CAPS];
            #pragma unroll
            for (int j = 0; j < OUT_CAPS; ++j) {
                float acc = 0.f;
                #pragma unroll
                for (int k = 0; k < IN_DIM; ++k)
                    acc = fmaf(xk[k], wp[j * (IN_DIM * OUT_DIM) + k * OUT_DIM], acc);
                u[j] = acc;
            }

            if (pass == 0) {
                // c = softmax(0) = 1/10 exactly
                #pragma unroll
                for (int j = 0; j < OUT_CAPS; ++j)
                    s_loc[j] = fmaf(0.1f, u[j], s_loc[j]);
            } else {
                // logit[j] = sum_d vdot[j][d] * u[j][d]  (16-lane butterfly)
                float logit[OUT_CAPS];
                #pragma unroll
                for (int j = 0; j < OUT_CAPS; ++j) {
                    float t = vdot_reg[j] * u[j];
                    t += __shfl_xor(t, 1);
                    t += __shfl_xor(t, 2);
                    t += __shfl_xor(t, 4);
                    t += __shfl_xor(t, 8);
                    logit[j] = t;
                }
                // softmax over j (lane-local, all lanes hold full logits)
                float m = logit[0];
                #pragma unroll
                for (int j = 1; j < OUT_CAPS; ++j) m = fmaxf(m, logit[j]);
                float Z = 0.f;
                float e[OUT_CAPS];
                #pragma unroll
                for (int j = 0; j < OUT_CAPS; ++j) { e[j] = expf(logit[j] - m); Z += e[j]; }
                const float invZ = 1.0f / Z;
                #pragma unroll
                for (int j = 0; j < OUT_CAPS; ++j)
                    s_loc[j] = fmaf(e[j] * invZ, u[j], s_loc[j]);
            }
        }

        // ---- block reduction of s over groups ----
        #pragma unroll
        for (int j = 0; j < OUT_CAPS; ++j)
            sred[g * (OUT_CAPS * OUT_DIM) + j * OUT_DIM + d] = s_loc[j];
        __syncthreads();

        if (tid < OUT_CAPS * OUT_DIM) {
            float s = 0.f;
            #pragma unroll 8
            for (int gg = 0; gg < NGROUPS; ++gg)
                s += sred[gg * (OUT_CAPS * OUT_DIM) + tid];

            // squash: norm over d; tid = j*16 + d so 16-lane groups align with j
            float t = s * s;
            t += __shfl_xor(t, 1);
            t += __shfl_xor(t, 2);
            t += __shfl_xor(t, 4);
            t += __shfl_xor(t, 8);
            const float scale = t / (1.0f + t) / sqrtf(t + 1e-7f);
            const float v = scale * s;

            if (pass == 2) {
                out[(size_t)b * (OUT_CAPS * OUT_DIM) + tid] = v;
            } else {
                vdot_lds[tid] = (pass == 0) ? v : (vdot_lds[tid] + v);
            }
        }
        __syncthreads();
    }
}

extern "C" void kernel_launch(void* const* d_in, const int* in_sizes, int n_in,
                              void* d_out, int out_size, void* d_ws, size_t ws_size,
                              hipStream_t stream) {
    const float* x = (const float*)d_in[0];
    const float* W = (const float*)d_in[1];
    float* out = (float*)d_out;
    hipLaunchKernelGGL(caps_routing_kernel, dim3(B_SZ), dim3(BLOCK_THREADS), 0, stream,
                       x, W, out);
}